// Round 3
// baseline (604.300 us; speedup 1.0000x reference)
//
#include <hip/hip_runtime.h>

// x = (B,1,1024,1024) fp32. Pre-CLAHE chain collapses exactly to
// (x - min)/(max - min). Single fused kernel with hand-rolled grid barriers:
// phase A: per-tile register load + global min/max
// phase B: histogram from registers -> clip -> scan -> LUT, write u8 bins
// phase C: strip apply with LDS-staged LUT rows.
// ws layout: mm[0..1]=min/max enc, mm[2..3]=barrier counters; lut @ +256; bins after.

#define BINS 256
#define MAXV 2560u        // int(40 * 16384 / 256)

__device__ __forceinline__ unsigned fenc(float f){
  unsigned u = __float_as_uint(f);
  return (u & 0x80000000u) ? ~u : (u | 0x80000000u);
}
__device__ __forceinline__ float fdec(unsigned e){
  unsigned u = (e & 0x80000000u) ? (e & 0x7FFFFFFFu) : ~e;
  return __uint_as_float(u);
}

__global__ void k_init(unsigned* mm, const int* __restrict__ y,
                       float* __restrict__ out, int N, int tail){
  int t = threadIdx.x;
  if (t == 0){ mm[0] = 0xFFFFFFFFu; mm[1] = 0u; mm[2] = 0u; mm[3] = 0u; }
  if (t < tail) out[N + t] = (float)y[t];
}

// grid barrier: one atomic arrive per block, thread-0 spins, agent scope.
// Counters pre-zeroed by k_init. A poisoned (0xAA..) counter exceeds nb,
// so a stray standalone replay falls through instead of deadlocking.
__device__ __forceinline__ void gridbar(unsigned* bar, unsigned nb){
  __syncthreads();
  if (threadIdx.x == 0){
    __threadfence();
    __hip_atomic_fetch_add(bar, 1u, __ATOMIC_ACQ_REL, __HIP_MEMORY_SCOPE_AGENT);
    while (__hip_atomic_load(bar, __ATOMIC_ACQUIRE, __HIP_MEMORY_SCOPE_AGENT) < nb)
      __builtin_amdgcn_s_sleep(8);
  }
  __syncthreads();
}

__global__ __launch_bounds__(256, 4)
void k_fused(const float* __restrict__ x, unsigned* mm,
             float* __restrict__ lutg, unsigned char* __restrict__ bins,
             float* __restrict__ out){
  __shared__ unsigned hist8[8 * 257 + 260];   // 8 hist copies + scan(256) + wsum(4)
  __shared__ float l01[4096];                 // phase C: two LUT rows
  int t = threadIdx.x;
  int tile = blockIdx.x;
  unsigned nb = gridDim.x;
  int bc = tile >> 6, ti = (tile >> 3) & 7, tj = tile & 7;
  size_t tbase = ((size_t)bc * 1024 + ti * 128) * 1024 + tj * 128;
  const float4* x4 = (const float4*)(x + tbase);

  // ---- phase A: load own 128x128 tile into registers, reduce min/max ----
  float4 v[16];
  #pragma unroll
  for (int k = 0; k < 16; k++){
    int p = t + (k << 8);                // 32 float4 per 128-px row
    v[k] = x4[(p >> 5) * 256 + (p & 31)];
  }
  float lmin = INFINITY, lmax = -INFINITY;
  #pragma unroll
  for (int k = 0; k < 16; k++){
    lmin = fminf(lmin, fminf(fminf(v[k].x, v[k].y), fminf(v[k].z, v[k].w)));
    lmax = fmaxf(lmax, fmaxf(fmaxf(v[k].x, v[k].y), fmaxf(v[k].z, v[k].w)));
  }
  for (int o = 32; o > 0; o >>= 1){
    lmin = fminf(lmin, __shfl_down(lmin, o, 64));
    lmax = fmaxf(lmax, __shfl_down(lmax, o, 64));
  }
  if ((t & 63) == 0){
    atomicMin(&mm[0], fenc(lmin));
    atomicMax(&mm[1], fenc(lmax));
  }
  gridbar(&mm[2], nb);

  // ---- phase B: histogram from registers, clip/scan/LUT, write u8 bins ----
  for (int i = t; i < 8 * 257; i += 256) hist8[i] = 0u;
  __syncthreads();
  float mn = fdec(__hip_atomic_load(&mm[0], __ATOMIC_RELAXED, __HIP_MEMORY_SCOPE_AGENT));
  float mx = fdec(__hip_atomic_load(&mm[1], __ATOMIC_RELAXED, __HIP_MEMORY_SCOPE_AGENT));
  float inv = 1.0f / (mx - mn);
  uchar4* b4 = (uchar4*)(bins + tbase);
  unsigned hc = (t & 7) * 257;
  #pragma unroll 4
  for (int k = 0; k < 16; k++){
    int p = t + (k << 8);
    int row = p >> 5, col = p & 31;
    int b0 = min(max((int)(((v[k].x - mn) * inv) * 256.0f), 0), 255);
    int b1 = min(max((int)(((v[k].y - mn) * inv) * 256.0f), 0), 255);
    int b2 = min(max((int)(((v[k].z - mn) * inv) * 256.0f), 0), 255);
    int b3 = min(max((int)(((v[k].w - mn) * inv) * 256.0f), 0), 255);
    b4[row * 256 + col] = make_uchar4((unsigned char)b0, (unsigned char)b1,
                                      (unsigned char)b2, (unsigned char)b3);
    atomicAdd(&hist8[hc + b0], 1u);
    atomicAdd(&hist8[hc + b1], 1u);
    atomicAdd(&hist8[hc + b2], 1u);
    atomicAdd(&hist8[hc + b3], 1u);
  }
  __syncthreads();
  unsigned h = 0;
  #pragma unroll
  for (int c = 0; c < 8; c++) h += hist8[c * 257 + t];
  if (h > MAXV) h = MAXV;
  unsigned* sc = hist8 + 8 * 257;
  unsigned* wsum = sc + 256;
  unsigned s = h;
  for (int o = 32; o > 0; o >>= 1) s += __shfl_down(s, o, 64);
  if ((t & 63) == 0) wsum[t >> 6] = s;
  __syncthreads();
  unsigned total = wsum[0] + wsum[1] + wsum[2] + wsum[3];
  float residual = (16384.0f - (float)total) * (1.0f / 256.0f);
  sc[t] = h;
  __syncthreads();
  for (int o = 1; o < 256; o <<= 1){
    unsigned pv = (t >= o) ? sc[t - o] : 0u;
    __syncthreads();
    sc[t] += pv;
    __syncthreads();
  }
  float cum = ((float)sc[t] + (float)(t + 1) * residual) * (255.0f / 16384.0f);
  lutg[(size_t)tile * BINS + t] = floorf(fminf(fmaxf(cum, 0.0f), 255.0f));
  gridbar(&mm[3], nb);

  // ---- phase C: strip apply (block = 16-row strip; i0/i1 uniform) ----
  int b = tile >> 6;
  int r0 = (tile & 63) << 4;
  float gi = fminf(fmaxf((r0 + 0.5f) * (1.0f / 128.0f) - 0.5f, 0.0f), 7.0f);
  int i0 = (int)gi;
  int i1 = min(i0 + 1, 7);
  float* l0s = l01;
  float* l1s = l01 + 2048;
  const float4* g0 = (const float4*)(lutg + ((size_t)b * 8 + i0) * 2048);
  const float4* g1 = (const float4*)(lutg + ((size_t)b * 8 + i1) * 2048);
  ((float4*)l0s)[t]       = g0[t];
  ((float4*)l0s)[t + 256] = g0[t + 256];
  ((float4*)l1s)[t]       = g1[t];
  ((float4*)l1s)[t + 256] = g1[t + 256];
  int j0[4], j1[4];
  float wx[4];
  #pragma unroll
  for (int c = 0; c < 4; c++){
    int col = (t << 2) + c;
    float gj = fminf(fmaxf((col + 0.5f) * (1.0f / 128.0f) - 0.5f, 0.0f), 7.0f);
    j0[c] = (int)gj;
    j1[c] = min(j0[c] + 1, 7);
    wx[c] = gj - (float)j0[c];
  }
  size_t base4 = ((size_t)b * 1024 + r0) * 256;   // float4 units
  const uchar4* binsq = (const uchar4*)bins;
  __syncthreads();
  for (int r = 0; r < 16; r++){
    int hh = r0 + r;
    float giw = fminf(fmaxf((hh + 0.5f) * (1.0f / 128.0f) - 0.5f, 0.0f), 7.0f);
    float wy = giw - (float)i0;
    uchar4 bv = binsq[base4 + r * 256 + t];
    int bi[4] = {bv.x, bv.y, bv.z, bv.w};
    float res[4];
    #pragma unroll
    for (int c = 0; c < 4; c++){
      float v00 = l0s[(j0[c] << 8) + bi[c]];
      float v01 = l0s[(j1[c] << 8) + bi[c]];
      float v10 = l1s[(j0[c] << 8) + bi[c]];
      float v11 = l1s[(j1[c] << 8) + bi[c]];
      float top = v00 + wx[c] * (v01 - v00);
      float bot = v10 + wx[c] * (v11 - v10);
      res[c] = (top + wy * (bot - top)) * (1.0f / 255.0f);
    }
    ((float4*)out)[base4 + r * 256 + t] = make_float4(res[0], res[1], res[2], res[3]);
  }
}

extern "C" void kernel_launch(void* const* d_in, const int* in_sizes, int n_in,
                              void* d_out, int out_size, void* d_ws, size_t ws_size,
                              hipStream_t stream){
  const float* x = (const float*)d_in[0];
  const int* y = (const int*)d_in[1];
  float* out = (float*)d_out;
  int N = in_sizes[0];
  int B = N >> 20;
  unsigned* mm = (unsigned*)d_ws;
  float* lut = (float*)((char*)d_ws + 256);
  size_t lutbytes = (size_t)B * 64 * 256 * 4;
  unsigned char* bins = (unsigned char*)d_ws + 256 + lutbytes;
  int tail = out_size - N;

  hipLaunchKernelGGL(k_init, dim3(1), dim3(64), 0, stream, mm, y, out, N, tail);
  hipLaunchKernelGGL(k_fused, dim3(B * 64), dim3(256), 0, stream,
                     x, mm, lut, bins, out);
}

// Round 4
// 135.534 us; speedup vs baseline: 4.4587x; 4.4587x over previous
//
#include <hip/hip_runtime.h>

// x = (B,1,1024,1024) fp32. Pre-CLAHE chain collapses exactly to
// (x - min)/(max - min). 3 dispatches, no global atomics, no grid barrier:
//   k_minmax: per-block min/max partials (+ y-tail write from block 0)
//   k_hist  : reduce partials in-block -> tile histogram -> clip/scan -> LUT,
//             writes u8 bin indices
//   k_apply : strip apply, LDS-staged LUT rows, u8 bins in, float4 out
// ws layout: partials float2[1024] @ 0 ; lut @ 8192 ; bins after lut.

#define BINS 256
#define MAXV 2560u        // int(40 * 16384 / 256)

__global__ __launch_bounds__(256) void k_minmax(const float4* __restrict__ x4,
                                                float2* __restrict__ partials,
                                                const int* __restrict__ y,
                                                float* __restrict__ out,
                                                int N, int tail, int n4){
  int tid = blockIdx.x * 256 + threadIdx.x;
  int stride = gridDim.x * 256;
  float lmin = INFINITY, lmax = -INFINITY;
  for (int i = tid; i < n4; i += stride){
    float4 v = x4[i];
    lmin = fminf(lmin, fminf(fminf(v.x, v.y), fminf(v.z, v.w)));
    lmax = fmaxf(lmax, fmaxf(fmaxf(v.x, v.y), fmaxf(v.z, v.w)));
  }
  for (int o = 32; o > 0; o >>= 1){
    lmin = fminf(lmin, __shfl_down(lmin, o, 64));
    lmax = fmaxf(lmax, __shfl_down(lmax, o, 64));
  }
  __shared__ float smin[4], smax[4];
  int lane = threadIdx.x & 63, wv = threadIdx.x >> 6;
  if (lane == 0){ smin[wv] = lmin; smax[wv] = lmax; }
  __syncthreads();
  if (threadIdx.x == 0){
    float m = smin[0], M = smax[0];
    #pragma unroll
    for (int i = 1; i < 4; i++){ m = fminf(m, smin[i]); M = fmaxf(M, smax[i]); }
    partials[blockIdx.x] = make_float2(m, M);
  }
  if (blockIdx.x == 0 && threadIdx.x < tail)
    out[N + threadIdx.x] = (float)y[threadIdx.x];
}

// one block per 128x128 tile
__global__ __launch_bounds__(256) void k_hist(const float* __restrict__ x,
                                              const float2* __restrict__ partials,
                                              int nparts,
                                              float* __restrict__ lut,
                                              unsigned char* __restrict__ bins){
  __shared__ unsigned hist8[8 * 257];
  __shared__ unsigned wsum[4];
  __shared__ unsigned sc[BINS];
  __shared__ float smn, sinv;
  __shared__ float smin[4], smax[4];
  int t = threadIdx.x;
  // ---- reduce the 1024 min/max partials (L2-hot, same for every block) ----
  float lmin = INFINITY, lmax = -INFINITY;
  for (int i = t; i < nparts; i += 256){
    float2 p = partials[i];
    lmin = fminf(lmin, p.x);
    lmax = fmaxf(lmax, p.y);
  }
  for (int o = 32; o > 0; o >>= 1){
    lmin = fminf(lmin, __shfl_down(lmin, o, 64));
    lmax = fmaxf(lmax, __shfl_down(lmax, o, 64));
  }
  int lane = t & 63, wv = t >> 6;
  if (lane == 0){ smin[wv] = lmin; smax[wv] = lmax; }
  for (int i = t; i < 8 * 257; i += 256) hist8[i] = 0u;
  __syncthreads();
  if (t == 0){
    float m = smin[0], M = smax[0];
    #pragma unroll
    for (int i = 1; i < 4; i++){ m = fminf(m, smin[i]); M = fmaxf(M, smax[i]); }
    smn = m;
    sinv = 1.0f / (M - m);
  }
  __syncthreads();
  float mn = smn, inv = sinv;
  // ---- histogram (8 privatized copies, stride 257) + u8 bin write ----
  int tile = blockIdx.x;
  int bc = tile >> 6, ti = (tile >> 3) & 7, tj = tile & 7;
  size_t base = ((size_t)bc * 1024 + ti * 128) * 1024 + tj * 128;
  const float4* x4 = (const float4*)(x + base);
  uchar4* b4 = (uchar4*)(bins + base);
  unsigned hc = (t & 7) * 257;
  #pragma unroll 4
  for (int k = 0; k < 16; k++){
    int p = t + (k << 8);           // 32 float4 per 128-px row
    int row = p >> 5, col = p & 31;
    float4 v = x4[row * 256 + col];
    int b0 = min(max((int)(((v.x - mn) * inv) * 256.0f), 0), 255);
    int b1 = min(max((int)(((v.y - mn) * inv) * 256.0f), 0), 255);
    int b2 = min(max((int)(((v.z - mn) * inv) * 256.0f), 0), 255);
    int b3 = min(max((int)(((v.w - mn) * inv) * 256.0f), 0), 255);
    b4[row * 256 + col] = make_uchar4((unsigned char)b0, (unsigned char)b1,
                                      (unsigned char)b2, (unsigned char)b3);
    atomicAdd(&hist8[hc + b0], 1u);
    atomicAdd(&hist8[hc + b1], 1u);
    atomicAdd(&hist8[hc + b2], 1u);
    atomicAdd(&hist8[hc + b3], 1u);
  }
  __syncthreads();
  unsigned h = 0;
  #pragma unroll
  for (int c = 0; c < 8; c++) h += hist8[c * 257 + t];
  if (h > MAXV) h = MAXV;
  unsigned s = h;
  for (int o = 32; o > 0; o >>= 1) s += __shfl_down(s, o, 64);
  if (lane == 0) wsum[wv] = s;
  __syncthreads();
  unsigned total = wsum[0] + wsum[1] + wsum[2] + wsum[3];
  float residual = (16384.0f - (float)total) * (1.0f / 256.0f);
  sc[t] = h;
  __syncthreads();
  for (int o = 1; o < 256; o <<= 1){
    unsigned pv = (t >= o) ? sc[t - o] : 0u;
    __syncthreads();
    sc[t] += pv;
    __syncthreads();
  }
  float cum = ((float)sc[t] + (float)(t + 1) * residual) * (255.0f / 16384.0f);
  lut[(size_t)tile * BINS + t] = floorf(fminf(fmaxf(cum, 0.0f), 255.0f));
}

// one block = 16-row strip of one image (i0/i1 uniform within a strip:
// band boundaries h=64+128k are 16-aligned). LUT rows staged in LDS.
__global__ __launch_bounds__(256) void k_apply(const uchar4* __restrict__ binsq,
                                               const float* __restrict__ lutg,
                                               float* __restrict__ out){
  __shared__ float l0s[2048];
  __shared__ float l1s[2048];
  int t = threadIdx.x;
  int strip = blockIdx.x;
  int b = strip >> 6;
  int r0 = (strip & 63) << 4;
  float gi = fminf(fmaxf((r0 + 0.5f) * (1.0f / 128.0f) - 0.5f, 0.0f), 7.0f);
  int i0 = (int)gi;
  int i1 = min(i0 + 1, 7);
  const float4* g0 = (const float4*)(lutg + ((size_t)b * 8 + i0) * 2048);
  const float4* g1 = (const float4*)(lutg + ((size_t)b * 8 + i1) * 2048);
  ((float4*)l0s)[t]       = g0[t];
  ((float4*)l0s)[t + 256] = g0[t + 256];
  ((float4*)l1s)[t]       = g1[t];
  ((float4*)l1s)[t + 256] = g1[t + 256];
  int j0[4], j1[4];
  float wx[4];
  #pragma unroll
  for (int c = 0; c < 4; c++){
    int col = (t << 2) + c;
    float gj = fminf(fmaxf((col + 0.5f) * (1.0f / 128.0f) - 0.5f, 0.0f), 7.0f);
    j0[c] = (int)gj;
    j1[c] = min(j0[c] + 1, 7);
    wx[c] = gj - (float)j0[c];
  }
  size_t base4 = ((size_t)b * 1024 + r0) * 256;   // float4 units
  __syncthreads();
  for (int r = 0; r < 16; r++){
    int h = r0 + r;
    float giw = fminf(fmaxf((h + 0.5f) * (1.0f / 128.0f) - 0.5f, 0.0f), 7.0f);
    float wy = giw - (float)i0;
    uchar4 bv = binsq[base4 + r * 256 + t];
    int bi[4] = {bv.x, bv.y, bv.z, bv.w};
    float res[4];
    #pragma unroll
    for (int c = 0; c < 4; c++){
      float v00 = l0s[(j0[c] << 8) + bi[c]];
      float v01 = l0s[(j1[c] << 8) + bi[c]];
      float v10 = l1s[(j0[c] << 8) + bi[c]];
      float v11 = l1s[(j1[c] << 8) + bi[c]];
      float top = v00 + wx[c] * (v01 - v00);
      float bot = v10 + wx[c] * (v11 - v10);
      res[c] = (top + wy * (bot - top)) * (1.0f / 255.0f);
    }
    ((float4*)out)[base4 + r * 256 + t] = make_float4(res[0], res[1], res[2], res[3]);
  }
}

extern "C" void kernel_launch(void* const* d_in, const int* in_sizes, int n_in,
                              void* d_out, int out_size, void* d_ws, size_t ws_size,
                              hipStream_t stream){
  const float* x = (const float*)d_in[0];
  const int* y = (const int*)d_in[1];
  float* out = (float*)d_out;
  int N = in_sizes[0];
  int B = N >> 20;
  int n4 = N >> 2;
  const int NPARTS = 1024;
  float2* partials = (float2*)d_ws;
  float* lut = (float*)((char*)d_ws + 8192);
  size_t lutbytes = (size_t)B * 64 * 256 * 4;
  unsigned char* bins = (unsigned char*)d_ws + 8192 + lutbytes;
  int tail = out_size - N;

  hipLaunchKernelGGL(k_minmax, dim3(NPARTS), dim3(256), 0, stream,
                     (const float4*)x, partials, y, out, N, tail, n4);
  hipLaunchKernelGGL(k_hist, dim3(B * 64), dim3(256), 0, stream,
                     x, partials, NPARTS, lut, bins);
  hipLaunchKernelGGL(k_apply, dim3(B * 64), dim3(256), 0, stream,
                     (const uchar4*)bins, lut, out);
}